// Round 6
// baseline (173.911 us; speedup 1.0000x reference)
//
#include <hip/hip_runtime.h>
#include <hip/hip_bf16.h>

#define MDIM 49
#define INF 128
#define OUTF 128
#define BDIM 16384
#define BT 64
#define TILES_PER_BLOCK 4
#define BLOCKS_PER_M (BDIM / (BT * TILES_PER_BLOCK))   // 64

typedef __attribute__((ext_vector_type(8))) short bf16x8;
typedef __attribute__((ext_vector_type(4))) float f32x4;

static __device__ __forceinline__ short f2bf(float f) {
  __hip_bfloat16 h = __float2bfloat16(f);
  union { __hip_bfloat16 h; unsigned short u; } c;
  c.h = h;
  return (short)c.u;
}

static __device__ __forceinline__ bf16x8 cvt8(f32x4 a, f32x4 b) {
  bf16x8 r;
  r[0] = f2bf(a[0]); r[1] = f2bf(a[1]); r[2] = f2bf(a[2]); r[3] = f2bf(a[3]);
  r[4] = f2bf(b[0]); r[5] = f2bf(b[1]); r[6] = f2bf(b[2]); r[7] = f2bf(b[3]);
  return r;
}

// LDS barrier that does NOT drain vmcnt: ds-op ordering only (lgkmcnt).
// Private global prefetch loads (and stores) legally stay in flight across it.
static __device__ __forceinline__ void lds_barrier() {
  asm volatile("s_waitcnt lgkmcnt(0)\n\ts_barrier" ::: "memory");
}

__global__ __launch_bounds__(256) void so3_linear_kernel(
    const float* __restrict__ in, const float* __restrict__ wt,
    const float* __restrict__ bias, float* __restrict__ out) {
  const int m    = blockIdx.x;   // 0..48
  const int blk  = blockIdx.y;   // 0..BLOCKS_PER_M-1
  const int tid  = threadIdx.x;
  const int lane = tid & 63;
  const int wv   = tid >> 6;     // wave 0..3

  // expand_index: l = floor(sqrt(m))
  int l = 0;
  while ((l + 1) * (l + 1) <= m) ++l;

  // double-buffered bf16 tile; +8 shorts pad (272 B stride: 2-way alias = free)
  __shared__ short lds[2][BT][INF + 8];

  // ---- weight fragments (A operand): wave wv owns output cols [wv*32, wv*32+32)
  // A-frag: row index = lane&15 (the o), k = (lane>>4)*8 + 0..7
  const int colbase = wv * 32;
  const int r16     = lane & 15;
  const int krow    = (lane >> 4) * 8;
  const float* wl   = wt + (size_t)l * OUTF * INF;
  bf16x8 wfrag[2][4];  // [o-tile][k-step]
#pragma unroll
  for (int ct = 0; ct < 2; ++ct) {
    const float* wp = wl + (size_t)(colbase + ct * 16 + r16) * INF + krow;
#pragma unroll
    for (int ks = 0; ks < 4; ++ks) {
      f32x4 w0 = *(const f32x4*)(wp + ks * 32);
      f32x4 w1 = *(const f32x4*)(wp + ks * 32 + 4);
      wfrag[ct][ks] = cvt8(w0, w1);
    }
  }
  // bias per lane: this lane stores o = colbase + ct*16 + (lane>>4)*4 + j
  f32x4 biasadd[2];
#pragma unroll
  for (int ct = 0; ct < 2; ++ct) {
    biasadd[ct] = (m == 0)
        ? *(const f32x4*)(bias + colbase + ct * 16 + (lane >> 4) * 4)
        : (f32x4){0.f, 0.f, 0.f, 0.f};
  }

  // staging map: thread -> (row r0 + 16p, 8-float chunk c8)
  const int c8 = (tid & 15) * 8;
  const int r0 = tid >> 4;
  const int b0 = blk * (TILES_PER_BLOCK * BT);

  const size_t rowstride = (size_t)MDIM * INF;  // 6272 floats between consecutive b

  // prologue: prefetch tile 0 into registers
  f32x4 pf[8];
  {
    const float* ip = in + ((size_t)(b0 + r0) * MDIM + m) * INF + c8;
#pragma unroll
    for (int p = 0; p < 4; ++p) {
      pf[2 * p]     = *(const f32x4*)(ip + p * 16 * rowstride);
      pf[2 * p + 1] = *(const f32x4*)(ip + p * 16 * rowstride + 4);
    }
  }

  for (int tt = 0; tt < TILES_PER_BLOCK; ++tt) {
    // convert current tile regs -> bf16 LDS buffer tt&1
#pragma unroll
    for (int p = 0; p < 4; ++p) {
      *(bf16x8*)&lds[tt & 1][r0 + 16 * p][c8] = cvt8(pf[2 * p], pf[2 * p + 1]);
    }

    // issue next tile's global loads; they stay in flight across the
    // lgkm-only barrier and land under MFMA + stores.
    if (tt + 1 < TILES_PER_BLOCK) {
      const float* ip =
          in + ((size_t)(b0 + (tt + 1) * BT + r0) * MDIM + m) * INF + c8;
#pragma unroll
      for (int p = 0; p < 4; ++p) {
        pf[2 * p]     = *(const f32x4*)(ip + p * 16 * rowstride);
        pf[2 * p + 1] = *(const f32x4*)(ip + p * 16 * rowstride + 4);
      }
    }

    // single barrier per tile (dbuf): ds_writes to buf[tt&1] visible before
    // reads; next tile writes buf[tt&1 ^ 1] so laggard readers are safe.
    lds_barrier();

    // compute: D[o][b] = W x X. Wave covers 64 rows x its 32 o-cols, K=128.
    f32x4 acc[4][2];  // [b-tile][o-tile]
#pragma unroll
    for (int bt = 0; bt < 4; ++bt)
#pragma unroll
      for (int ct = 0; ct < 2; ++ct)
        acc[bt][ct] = (f32x4){0.f, 0.f, 0.f, 0.f};

#pragma unroll
    for (int bt = 0; bt < 4; ++bt) {
      const int arow = bt * 16 + r16;  // B-frag: col index = lane&15 (the b)
#pragma unroll
      for (int ks = 0; ks < 4; ++ks) {
        bf16x8 a = *(const bf16x8*)&lds[tt & 1][arow][ks * 32 + krow];
        acc[bt][0] = __builtin_amdgcn_mfma_f32_16x16x32_bf16(
            wfrag[0][ks], a, acc[bt][0], 0, 0, 0);
        acc[bt][1] = __builtin_amdgcn_mfma_f32_16x16x32_bf16(
            wfrag[1][ks], a, acc[bt][1], 0, 0, 0);
      }
    }

    // epilogue: D col(lane&15)=b, row((lane>>4)*4+j)=o -> f32x4 store per (bt,ct)
    const int btile = b0 + tt * BT;
#pragma unroll
    for (int bt = 0; bt < 4; ++bt) {
      const int b = btile + bt * 16 + r16;
      float* op = out + (size_t)b * rowstride + (size_t)m * OUTF + colbase +
                  (lane >> 4) * 4;
#pragma unroll
      for (int ct = 0; ct < 2; ++ct) {
        f32x4 v = acc[bt][ct];
        v[0] += biasadd[ct][0]; v[1] += biasadd[ct][1];
        v[2] += biasadd[ct][2]; v[3] += biasadd[ct][3];
        *(f32x4*)(op + ct * 16) = v;
      }
    }
  }
}

extern "C" void kernel_launch(void* const* d_in, const int* in_sizes, int n_in,
                              void* d_out, int out_size, void* d_ws, size_t ws_size,
                              hipStream_t stream) {
  const float* in   = (const float*)d_in[0];
  const float* wt   = (const float*)d_in[1];
  const float* bias = (const float*)d_in[2];
  float* out        = (float*)d_out;
  dim3 grid(MDIM, BLOCKS_PER_M);
  so3_linear_kernel<<<grid, dim3(256), 0, stream>>>(in, wt, bias, out);
}